// Round 7
// baseline (345.144 us; speedup 1.0000x reference)
//
#include <hip/hip_runtime.h>
#include <math.h>

typedef _Float16 f16_t;
typedef _Float16 half8 __attribute__((ext_vector_type(8)));
typedef float f32x4 __attribute__((ext_vector_type(4)));
typedef unsigned short u16;

#define T_SEQ 2048
#define H_DIM 2048
#define C_DIM 1024
#define B_SZ  4

// async global->LDS, 16B per lane. LDS dest = wave-uniform base + lane*16.
__device__ __forceinline__ void gload16(const void* g, void* l) {
  typedef const __attribute__((address_space(1))) unsigned int* gp_t;
  typedef __attribute__((address_space(3))) unsigned int* lp_t;
  __builtin_amdgcn_global_load_lds((gp_t)(unsigned long long)g,
                                   (lp_t)(unsigned int)(unsigned long long)l,
                                   16, 0, 0);
}

// -- 4-wave 16x16 core, BK=64 (2 sub-buffers, ONE barrier pair per 64-K) --
// LDS = 32 KB: A[2][128][32] f16 @0, B[2][128][32] f16 @16384.
__device__ __forceinline__ void gemm_tile64(const f16_t* __restrict__ A,
                                            const f16_t* __restrict__ B,
                                            int K, int k_end, int m0, int n0,
                                            char* lds, f32x4 acc[4][4]) {
  const int tid  = threadIdx.x;
  const int wave = tid >> 6;
  const int lane = tid & 63;
  const int wm = (wave & 1) << 6;
  const int wn = (wave >> 1) << 6;
  const int srow = tid >> 2;
  const int scol = ((tid & 3) ^ ((tid >> 3) & 3)) << 3;     // swizzled fetch chunk
  const int fm = lane & 15;
  const int fks = (((lane >> 4) ^ ((lane >> 1) & 3)) << 3); // swizzled read offset
  const f16_t* As = (const f16_t*)lds;
  const f16_t* Bs = (const f16_t*)(lds + 16384);
  char* ldsA = lds + (wave << 10);
  char* ldsB = lds + 16384 + (wave << 10);
  const f16_t* Ap0 = A + (size_t)(m0 + srow) * K + scol;
  const f16_t* Ap1 = A + (size_t)(m0 + 64 + srow) * K + scol;
  const f16_t* Bp0 = B + (size_t)(n0 + srow) * K + scol;
  const f16_t* Bp1 = B + (size_t)(n0 + 64 + srow) * K + scol;
  for (int k0 = 0; k0 < k_end; k0 += 64) {
    gload16(Ap0 + k0, ldsA);
    gload16(Ap1 + k0, ldsA + 4096);
    gload16(Ap0 + k0 + 32, ldsA + 8192);
    gload16(Ap1 + k0 + 32, ldsA + 12288);
    gload16(Bp0 + k0, ldsB);
    gload16(Bp1 + k0, ldsB + 4096);
    gload16(Bp0 + k0 + 32, ldsB + 8192);
    gload16(Bp1 + k0 + 32, ldsB + 12288);
    __syncthreads();
#pragma unroll
    for (int s = 0; s < 2; ++s) {
      const f16_t* As_s = As + (s << 12);
      const f16_t* Bs_s = Bs + (s << 12);
      half8 af[4], bfr[4];
#pragma unroll
      for (int i = 0; i < 4; ++i)
        af[i] = *(const half8*)(As_s + ((wm + i * 16 + fm) << 5) + fks);
#pragma unroll
      for (int j = 0; j < 4; ++j)
        bfr[j] = *(const half8*)(Bs_s + ((wn + j * 16 + fm) << 5) + fks);
#pragma unroll
      for (int i = 0; i < 4; ++i)
#pragma unroll
        for (int j = 0; j < 4; ++j)
          acc[i][j] = __builtin_amdgcn_mfma_f32_16x16x32_f16(af[i], bfr[j], acc[i][j], 0, 0, 0);
    }
    __syncthreads();
  }
}

// -- 8-wave 128m x 256n core, BK=64 (R7, for k_pv): waves 2m x 4n, 64x64 each.
// LDS = 48 KB: A[2][128][32] @0 (16KB), B[2][256][32] @16384 (32KB).
// Same swizzle/fragment math as gemm_tile64 (0 bank conflicts measured there);
// same K order per output element -> numerics identical to the 128n version.
// Mechanism: n-extent 256 halves the number of blocks staging each A(P)
// panel -> A traffic 285 -> 143 MB.
__device__ __forceinline__ void gemm_tile64_w8(const f16_t* __restrict__ A,
                                               const f16_t* __restrict__ B,
                                               int K, int k_end, int m0, int n0,
                                               char* lds, f32x4 acc[4][4]) {
  const int tid  = threadIdx.x;            // 0..511
  const int wave = tid >> 6;
  const int lane = tid & 63;
  const int wm = (wave >> 2) << 6;         // 0,64
  const int wn = (wave & 3) << 6;          // 0,64,128,192
  const int srow = tid >> 2;               // 0..127
  const int scol = ((tid & 3) ^ ((tid >> 3) & 3)) << 3;     // swizzled fetch chunk
  const int fm = lane & 15;
  const int fks = (((lane >> 4) ^ ((lane >> 1) & 3)) << 3); // swizzled read offset
  const f16_t* As = (const f16_t*)lds;
  const f16_t* Bs = (const f16_t*)(lds + 16384);
  char* ldsAw = lds + (wave << 10);
  char* ldsBw = lds + 16384 + (wave << 10);
  const f16_t* Ap  = A + (size_t)(m0 + srow) * K + scol;
  const f16_t* Bp0 = B + (size_t)(n0 + srow) * K + scol;
  const f16_t* Bp1 = B + (size_t)(n0 + 128 + srow) * K + scol;
  for (int k0 = 0; k0 < k_end; k0 += 64) {
    gload16(Ap + k0, ldsAw);                 // A rows 0-127, k sub0
    gload16(Ap + k0 + 32, ldsAw + 8192);     // A sub1
    gload16(Bp0 + k0, ldsBw);                // B rows 0-127, sub0
    gload16(Bp1 + k0, ldsBw + 8192);         // B rows 128-255, sub0
    gload16(Bp0 + k0 + 32, ldsBw + 16384);   // B rows 0-127, sub1
    gload16(Bp1 + k0 + 32, ldsBw + 24576);   // B rows 128-255, sub1
    __syncthreads();
#pragma unroll
    for (int s = 0; s < 2; ++s) {
      const f16_t* As_s = As + (s << 12);    // 8KB sub
      const f16_t* Bs_s = Bs + (s << 13);    // 16KB sub
      half8 af[4], bfr[4];
#pragma unroll
      for (int i = 0; i < 4; ++i)
        af[i] = *(const half8*)(As_s + ((wm + i * 16 + fm) << 5) + fks);
#pragma unroll
      for (int j = 0; j < 4; ++j)
        bfr[j] = *(const half8*)(Bs_s + ((wn + j * 16 + fm) << 5) + fks);
#pragma unroll
      for (int i = 0; i < 4; ++i)
#pragma unroll
        for (int j = 0; j < 4; ++j)
          acc[i][j] = __builtin_amdgcn_mfma_f32_16x16x32_f16(af[i], bfr[j], acc[i][j], 0, 0, 0);
    }
    __syncthreads();
  }
}

// =================== 256x256 8-phase GEMM core (k_proj) =====================
// R3/R4: FETCH 203->74 MB via XCD swizzle, time pinned ~111-118us. Parked.

#define P_BAR  __builtin_amdgcn_s_barrier()
#define P_SB   __builtin_amdgcn_sched_barrier(0)
#define P_WL   asm volatile("s_waitcnt lgkmcnt(0)" ::: "memory")
#define P_WL8  asm volatile("s_waitcnt lgkmcnt(8)" ::: "memory")
#define P_WV4  asm volatile("s_waitcnt vmcnt(4)" ::: "memory")
#define P_WV0  asm volatile("s_waitcnt vmcnt(0)" ::: "memory")
#define P_HI   __builtin_amdgcn_s_setprio(1)
#define P_LO   __builtin_amdgcn_s_setprio(0)

#define STAGE_A(buf, h, kt) do { if ((kt) < NT) {                          \
    const f16_t* g_ = Ag + (size_t)((h) * 128) * KD + (kt) * 64;           \
    char* d_ = ldsAw + (buf) * 65536 + (h) * 16384;                        \
    gload16(g_, d_); gload16(g_ + (size_t)64 * KD, d_ + 8192); } } while (0)

#define STAGE_B(buf, h, kt) do { if ((kt) < NT) {                          \
    const f16_t* g_ = Bg + (size_t)((h) * 128) * KD + (kt) * 64;           \
    char* d_ = ldsBw + (buf) * 65536 + (h) * 16384;                        \
    gload16(g_, d_); gload16(g_ + (size_t)64 * KD, d_ + 8192); } } while (0)

#define LDA8(mh, buf) do {                                                 \
    const char* p_ = ldsAr + (buf) * 65536 + (mh) * 8192;                  \
    _Pragma("unroll")                                                      \
    for (int i_ = 0; i_ < 4; ++i_) {                                       \
      af[i_][0] = *(const half8*)(p_ + (i_ << 11) + u0);                   \
      af[i_][1] = *(const half8*)(p_ + (i_ << 11) + u1); } } while (0)

#define LDB4(nh, buf) do {                                                 \
    const char* p_ = ldsBr + (buf) * 65536 + (nh) * 4096;                  \
    _Pragma("unroll")                                                      \
    for (int j_ = 0; j_ < 2; ++j_) {                                       \
      bf[nh][j_][0] = *(const half8*)(p_ + (j_ << 11) + u0);               \
      bf[nh][j_][1] = *(const half8*)(p_ + (j_ << 11) + u1); } } while (0)

#define MMQ(mh, nh) do {                                                   \
    _Pragma("unroll")                                                      \
    for (int i_ = 0; i_ < 4; ++i_)                                         \
    _Pragma("unroll")                                                      \
    for (int j_ = 0; j_ < 2; ++j_) {                                       \
      acc[(mh) * 4 + i_][(nh) * 2 + j_] =                                  \
        __builtin_amdgcn_mfma_f32_16x16x32_f16(af[i_][0], bf[nh][j_][0],   \
            acc[(mh) * 4 + i_][(nh) * 2 + j_], 0, 0, 0);                   \
      acc[(mh) * 4 + i_][(nh) * 2 + j_] =                                  \
        __builtin_amdgcn_mfma_f32_16x16x32_f16(af[i_][1], bf[nh][j_][1],   \
            acc[(mh) * 4 + i_][(nh) * 2 + j_], 0, 0, 0); } } while (0)

#define ITER_BODY(kt1, kt2, kt3, WAIT4) do {                               \
    /* ph1 */                                                              \
    LDA8(0, 0); LDB4(0, 0);                                                \
    STAGE_A(1, 0, kt1);                                                    \
    P_WL8; P_SB; P_BAR;                                                    \
    P_WL; P_SB;                                                            \
    P_HI; MMQ(0, 0); P_LO; P_SB;                                           \
    P_BAR;                                                                 \
    /* ph2 */                                                              \
    LDB4(1, 0);                                                            \
    STAGE_A(1, 1, kt1);                                                    \
    P_SB; P_BAR;                                                           \
    P_WL; P_SB;                                                            \
    P_HI; MMQ(0, 1); P_LO; P_SB;                                           \
    P_BAR;                                                                 \
    /* ph3 */                                                              \
    LDA8(1, 0);                                                            \
    STAGE_B(0, 0, kt2);                                                    \
    P_SB; P_BAR;                                                           \
    P_WL; P_SB;                                                            \
    P_HI; MMQ(1, 0); P_LO; P_SB;                                           \
    P_BAR;                                                                 \
    /* ph4: guard K-tile kt1 */                                            \
    STAGE_B(0, 1, kt2);                                                    \
    WAIT4; P_SB; P_BAR; P_SB;                                              \
    P_HI; MMQ(1, 1); P_LO; P_SB;                                           \
    P_BAR;                                                                 \
    /* ph5: compute K-tile kt1 (buf1) */                                   \
    LDA8(0, 1); LDB4(0, 1);                                                \
    STAGE_A(0, 0, kt2);                                                    \
    P_WL8; P_SB; P_BAR;                                                    \
    P_WL; P_SB;                                                            \
    P_HI; MMQ(0, 0); P_LO; P_SB;                                           \
    P_BAR;                                                                 \
    /* ph6 */                                                              \
    LDB4(1, 1);                                                            \
    STAGE_A(0, 1, kt2);                                                    \
    P_SB; P_BAR;                                                           \
    P_WL; P_SB;                                                            \
    P_HI; MMQ(0, 1); P_LO; P_SB;                                           \
    P_BAR;                                                                 \
    /* ph7 */                                                              \
    LDA8(1, 1);                                                            \
    STAGE_B(1, 0, kt3);                                                    \
    P_SB; P_BAR;                                                           \
    P_WL; P_SB;                                                            \
    P_HI; MMQ(1, 0); P_LO; P_SB;                                           \
    P_BAR;                                                                 \
    /* ph8: guard K-tile kt2 */                                            \
    STAGE_B(1, 1, kt3);                                                    \
    WAIT4; P_SB; P_BAR; P_SB;                                              \
    P_HI; MMQ(1, 1); P_LO; P_SB;                                           \
    P_BAR;                                                                 \
  } while (0)

// Merged Q/K/V projection: 256^2 tile, 8-phase counted-vmcnt schedule.
__global__ __launch_bounds__(512, 2)
void k_proj(const f16_t* __restrict__ X,
            const f16_t* __restrict__ Wq, const f16_t* __restrict__ Wk,
            const f16_t* __restrict__ Wv,
            f16_t* __restrict__ Qo, f16_t* __restrict__ Ko,
            u16* __restrict__ Vt) {
  __shared__ char lds[131072];
  constexpr int KD = C_DIM;      // 1024
  constexpr int NT = KD / 64;    // 16 K-tiles, 8 iterations
  const int z = blockIdx.z;
  const f16_t* W = (z == 0) ? Wq : (z == 1) ? Wk : Wv;
  // XCD chunk swizzle: 4y x 8x tile chunk per XCD (A fetched once/z).
  const int lin = (blockIdx.y << 3) | blockIdx.x;   // 0..255
  const int t_sw = ((lin & 7) << 5) + (lin >> 3);   // chunk c -> tiles [32c,32c+32)
  const int m0 = (t_sw >> 3) << 8, n0 = (t_sw & 7) << 8;

  const int tid = threadIdx.x, wave = tid >> 6, lane = tid & 63;
  const int wm = wave >> 2, wn = wave & 3;
  // staging: lane writes LDS (row = base + lane>>3, unit = lane&7);
  // row&7 == lane>>3, so pre-swizzled global chunk = (lane&7)^(lane>>3).
  const int srow = (wave << 3) + (lane >> 3);
  const int scol = (((lane & 7) ^ (lane >> 3)) << 3);
  const f16_t* Ag = X + (size_t)(m0 + srow) * KD + scol;
  const f16_t* Bg = W + (size_t)(n0 + srow) * KD + scol;
  char* ldsAw = lds + (wave << 10);
  char* ldsBw = lds + 32768 + (wave << 10);
  // ds_read de-swizzle: row&7 == lane&7; want chunk ks*4+(lane>>4).
  const int u0 = (((lane >> 4) ^ (lane & 7)) << 4);
  const int u1 = u0 ^ 64;
  const char* ldsAr = lds + ((wm * 128 + (lane & 15)) << 7);
  const char* ldsBr = lds + 32768 + ((wn * 64 + (lane & 15)) << 7);

  f32x4 acc[8][4];
#pragma unroll
  for (int i = 0; i < 8; ++i)
#pragma unroll
    for (int j = 0; j < 4; ++j) acc[i][j] = (f32x4){0.f, 0.f, 0.f, 0.f};
  half8 af[4][2], bf[2][2][2];

  // prologue: K-tile 0 full + B of K-tile 1 (A of K-tile 1 staged at ph1/ph2)
  STAGE_A(0, 0, 0); STAGE_A(0, 1, 0);
  STAGE_B(0, 0, 0); STAGE_B(0, 1, 0);
  STAGE_B(1, 0, 1); STAGE_B(1, 1, 1);
  P_WV4;     // K-tile 0 landed; B(1) may stay in flight
  P_SB; P_BAR; P_SB;

  for (int I = 0; I < NT / 2 - 1; ++I) {
    const int kt1 = 2 * I + 1, kt2 = 2 * I + 2, kt3 = 2 * I + 3;
    ITER_BODY(kt1, kt2, kt3, P_WV4);
  }
  // peeled final iteration: kt2/kt3 >= NT (stages skipped) -> must drain to 0
  ITER_BODY(NT - 1, NT, NT + 1, P_WV0);

  // epilogue: C/D 16x16 layout (m89): col = lane&15, row = (lane>>4)*4 + reg
  const int mb = m0 + wm * 128 + ((lane >> 4) << 2);
  const int nb = n0 + wn * 64 + (lane & 15);
  if (z < 2) {
    f16_t* Cb = z ? Ko : Qo;
#pragma unroll
    for (int ii = 0; ii < 8; ++ii)
#pragma unroll
      for (int jj = 0; jj < 4; ++jj) {
        const size_t base = (size_t)(mb + ii * 16) * H_DIM + (nb + jj * 16);
#pragma unroll
        for (int r = 0; r < 4; ++r)
          Cb[base + (size_t)r * H_DIM] = (f16_t)acc[ii][jj][r];
      }
  } else {
    // Vt transposed store: 4 consecutive t per frag -> line-combined ushort4
#pragma unroll
    for (int ii = 0; ii < 8; ++ii) {
      const int gm = mb + ii * 16;          // b*T + t
      const int b = gm >> 11;
      const int t = gm & (T_SEQ - 1);
#pragma unroll
      for (int jj = 0; jj < 4; ++jj) {
        const int h = nb + jj * 16;
        ushort4 pk;
        pk.x = __builtin_bit_cast(u16, (f16_t)acc[ii][jj][0]);
        pk.y = __builtin_bit_cast(u16, (f16_t)acc[ii][jj][1]);
        pk.z = __builtin_bit_cast(u16, (f16_t)acc[ii][jj][2]);
        pk.w = __builtin_bit_cast(u16, (f16_t)acc[ii][jj][3]);
        *(ushort4*)(Vt + ((size_t)(b * H_DIM + h) * T_SEQ + t)) = pk;
      }
    }
  }
}

// C/D layout 16x16 (verified m89): col = lane&15, row = (lane>>4)*4 + reg
#define EPI_PREAMBLE                                            \
  const int lane = threadIdx.x & 63;                            \
  const int wl_e = (threadIdx.x >> 6) & 3;                      \
  const int mb = m0 + ((wl_e & 1) << 6) + ((lane >> 4) << 2);   \
  const int nb = n0 + ((wl_e >> 1) << 6) + (lane & 15);

#define ZERO_ACC                                                \
  f32x4 acc[4][4];                                              \
  _Pragma("unroll")                                             \
  for (int i = 0; i < 4; ++i)                                   \
    _Pragma("unroll")                                           \
    for (int j = 0; j < 4; ++j) acc[i][j] = (f32x4){0.f, 0.f, 0.f, 0.f};

// scores: lower-triangle tiles, 4-wave BK=64 core.
// XCD map: XCD c owns complementary rows {15-c, c} (17 tiles, uniform).
__global__ __launch_bounds__(256, 2)
void k_scores(const f16_t* __restrict__ Q, const f16_t* __restrict__ Kc,
              f16_t* __restrict__ S) {
  __shared__ char lds[32768];
  ZERO_ACC
  const int x = blockIdx.x;                // 0..135; XCD = x & 7 (136 % 8 == 0)
  const int c = x & 7;
  const int t = x >> 3;                    // 0..16 within XCD chunk
  int i, j;
  if (t < 16 - c) { i = 15 - c; j = t; }   // big row first
  else            { i = c;      j = t - (16 - c); }
  const int b = blockIdx.y;
  const int m0 = i << 7, n0 = j << 7;
  const f16_t* Aq = Q + (size_t)b * T_SEQ * H_DIM;
  const f16_t* Bk = Kc + (size_t)b * T_SEQ * H_DIM;
  f16_t* Sb = S + (size_t)b * T_SEQ * T_SEQ;
  gemm_tile64(Aq, Bk, H_DIM, H_DIM, m0, n0, lds, acc);
  EPI_PREAMBLE
  const float scale = 0.022097086912079608f;  // 2048^-0.5
#pragma unroll
  for (int i2 = 0; i2 < 4; ++i2)
#pragma unroll
    for (int j2 = 0; j2 < 4; ++j2) {
      const size_t base = (size_t)(mb + i2 * 16) * T_SEQ + (nb + j2 * 16);
#pragma unroll
      for (int r = 0; r < 4; ++r)
        Sb[base + (size_t)r * T_SEQ] = (f16_t)(acc[i2][j2][r] * scale);
    }
}

// causal softmax: one row/block, one half8/thread, exp kept in registers.
// Writes zeros only up to n128 = ceil(n/128)*128 — exactly the region PV reads.
__global__ __launch_bounds__(256)
void k_softmax(const f16_t* __restrict__ S, f16_t* __restrict__ P) {
  const int row = blockIdx.x;              // b*T + t
  const int t = row & (T_SEQ - 1);
  const int n = t + 1;
  const int n128 = (n + 127) & ~127;
  const int tid = threadIdx.x;
  const int c0 = tid << 3;
  const f16_t* s = S + (size_t)row * T_SEQ;
  f16_t* p = P + (size_t)row * T_SEQ;
  __shared__ float red[8];
  half8 v;
  float lmax = -3.0e38f;
  if (c0 < n) {
    v = *(const half8*)(s + c0);
#pragma unroll
    for (int r = 0; r < 8; ++r)
      if (c0 + r < n) lmax = fmaxf(lmax, (float)v[r]);
  }
#pragma unroll
  for (int off = 32; off > 0; off >>= 1) lmax = fmaxf(lmax, __shfl_xor(lmax, off, 64));
  if ((tid & 63) == 0) red[tid >> 6] = lmax;
  __syncthreads();
  const float m = fmaxf(fmaxf(red[0], red[1]), fmaxf(red[2], red[3]));
  float e[8];
  float lsum = 0.f;
  if (c0 < n) {
#pragma unroll
    for (int r = 0; r < 8; ++r) {
      e[r] = (c0 + r < n) ? __expf((float)v[r] - m) : 0.f;
      lsum += e[r];
    }
  }
#pragma unroll
  for (int off = 32; off > 0; off >>= 1) lsum += __shfl_xor(lsum, off, 64);
  if ((tid & 63) == 0) red[4 + (tid >> 6)] = lsum;
  __syncthreads();
  const float inv = 1.0f / (red[4] + red[5] + red[6] + red[7]);
  if (c0 < n128) {
    half8 o;
#pragma unroll
    for (int r = 0; r < 8; ++r)
      o[r] = (c0 + r < n) ? (f16_t)(e[r] * inv) : (f16_t)0.f;
    *(half8*)(p + c0) = o;
  }
}

// PV, R7: 128m x 256n tiles (8-wave w8 core) with diagonal pairing — block
// (qp, n, b) computes m-tiles 15-qp and qp (uniform 17 K-units). 256 blocks
// of 512 thr, XCD = qp (kept from R6). A(P) staging traffic halves vs 128n.
__global__ __launch_bounds__(512, 2)
void k_pv(const f16_t* __restrict__ P, const f16_t* __restrict__ Vt,
          float* __restrict__ Out) {
  __shared__ char lds[49152];
  const int b = blockIdx.z;
  const int qp = blockIdx.x;               // 0..7 = XCD (gridDim.x = 8)
  const int n0 = blockIdx.y << 8;          // 0..7 -> 256-wide n-tile
  const f16_t* Ap = P + (size_t)b * T_SEQ * T_SEQ;
  const f16_t* Bv = Vt + (size_t)b * H_DIM * T_SEQ;
  float* Ob = Out + (size_t)b * T_SEQ * H_DIM;
  const int lane = threadIdx.x & 63;
  const int wave = threadIdx.x >> 6;
  const int wm = (wave >> 2) << 6;
  const int wn = (wave & 3) << 6;
#pragma unroll
  for (int u = 0; u < 2; ++u) {
    const int mi = u ? qp : (15 - qp);     // big K first
    const int m0 = mi << 7;
    ZERO_ACC
    gemm_tile64_w8(Ap, Bv, T_SEQ, m0 + 128, m0, n0, lds, acc);
    const int mb = m0 + wm + ((lane >> 4) << 2);
    const int nb = n0 + wn + (lane & 15);
#pragma unroll
    for (int i = 0; i < 4; ++i)
#pragma unroll
      for (int j = 0; j < 4; ++j) {
        const size_t base = (size_t)(mb + i * 16) * H_DIM + (nb + j * 16);
#pragma unroll
        for (int r = 0; r < 4; ++r)
          Ob[base + (size_t)r * H_DIM] = acc[i][j][r];
      }
    __syncthreads();   // LDS reuse barrier between the two m-tiles
  }
}

// one fused f32 -> f16 conversion pass over x, Wk, Wq, Wv
#define XN4 ((B_SZ * T_SEQ * C_DIM) / 4)   // 2097152
#define WN4 ((H_DIM * C_DIM) / 4)          // 524288
__global__ __launch_bounds__(256)
void k_cvt_all(const float4* __restrict__ x,  const float4* __restrict__ wk,
               const float4* __restrict__ wq, const float4* __restrict__ wv,
               ushort4* __restrict__ xb, ushort4* __restrict__ wkb,
               ushort4* __restrict__ wqb, ushort4* __restrict__ wvb) {
  int idx = blockIdx.x * 256 + threadIdx.x;
  const float4* src; ushort4* dst;
  if (idx < XN4)                { src = x;  dst = xb; }
  else if (idx < XN4 + WN4)     { src = wk; dst = wkb; idx -= XN4; }
  else if (idx < XN4 + 2 * WN4) { src = wq; dst = wqb; idx -= XN4 + WN4; }
  else                          { src = wv; dst = wvb; idx -= XN4 + 2 * WN4; }
  const float4 v = src[idx];
  ushort4 o;
  o.x = __builtin_bit_cast(u16, (f16_t)v.x);
  o.y = __builtin_bit_cast(u16, (f16_t)v.y);
  o.z = __builtin_bit_cast(u16, (f16_t)v.z);
  o.w = __builtin_bit_cast(u16, (f16_t)v.w);
  dst[idx] = o;
}

extern "C" void kernel_launch(void* const* d_in, const int* in_sizes, int n_in,
                              void* d_out, int out_size, void* d_ws, size_t ws_size,
                              hipStream_t stream) {
  (void)in_sizes; (void)n_in; (void)out_size; (void)ws_size;
  const float* x  = (const float*)d_in[0];
  const float* Wk = (const float*)d_in[1];
  const float* Wq = (const float*)d_in[2];
  const float* Wv = (const float*)d_in[3];
  float* out = (float*)d_out;
  char* ws = (char*)d_ws;
  // workspace (192 MB):
  //  [0,32M) q f16   [32M,64M) k f16   [64M,96M) Vt f16 [B,H,T]
  //  [96M,128M) S f16 [B,T,T]          [160M,192M) P f16
  //  cvt temps (dead before S written): xb@96M, wk@128M, wq@132M, wv@136M
  f16_t* qb  = (f16_t*)(ws);
  f16_t* kb  = (f16_t*)(ws + (32ull << 20));
  f16_t* vt  = (f16_t*)(ws + (64ull << 20));
  f16_t* S   = (f16_t*)(ws + (96ull << 20));
  f16_t* P   = (f16_t*)(ws + (160ull << 20));
  f16_t* xb  = (f16_t*)(ws + (96ull << 20));
  f16_t* wkb = (f16_t*)(ws + (128ull << 20));
  f16_t* wqb = (f16_t*)(ws + (132ull << 20));
  f16_t* wvb = (f16_t*)(ws + (136ull << 20));

  k_cvt_all<<<(XN4 + 3 * WN4) / 256, 256, 0, stream>>>(
      (const float4*)x, (const float4*)Wk, (const float4*)Wq, (const float4*)Wv,
      (ushort4*)xb, (ushort4*)wkb, (ushort4*)wqb, (ushort4*)wvb);

  dim3 gp(H_DIM / 256, (B_SZ * T_SEQ) / 256, 3);       // 8 x 32 x 3
  k_proj<<<gp, 512, 0, stream>>>(xb, wqb, wkb, wvb, qb, kb, (u16*)vt);

  dim3 gs(136, B_SZ);                                   // lower-triangle tiles
  k_scores<<<gs, 256, 0, stream>>>(qb, kb, S);
  k_softmax<<<B_SZ * T_SEQ, 256, 0, stream>>>(S, P);
  dim3 gv(8, H_DIM / 256, B_SZ);                        // x = q-pair = XCD
  k_pv<<<gv, 512, 0, stream>>>(P, vt, out);
}

// Round 8
// 341.413 us; speedup vs baseline: 1.0109x; 1.0109x over previous
//
#include <hip/hip_runtime.h>
#include <math.h>

typedef _Float16 f16_t;
typedef _Float16 half8 __attribute__((ext_vector_type(8)));
typedef float f32x4 __attribute__((ext_vector_type(4)));
typedef unsigned short u16;

#define T_SEQ 2048
#define H_DIM 2048
#define C_DIM 1024
#define B_SZ  4

// async global->LDS, 16B per lane. LDS dest = wave-uniform base + lane*16.
__device__ __forceinline__ void gload16(const void* g, void* l) {
  typedef const __attribute__((address_space(1))) unsigned int* gp_t;
  typedef __attribute__((address_space(3))) unsigned int* lp_t;
  __builtin_amdgcn_global_load_lds((gp_t)(unsigned long long)g,
                                   (lp_t)(unsigned int)(unsigned long long)l,
                                   16, 0, 0);
}

// -- 4-wave 16x16 core, BK=64 (2 sub-buffers, ONE barrier pair per 64-K) --
// LDS = 32 KB: A[2][128][32] f16 @0, B[2][128][32] f16 @16384.
__device__ __forceinline__ void gemm_tile64(const f16_t* __restrict__ A,
                                            const f16_t* __restrict__ B,
                                            int K, int k_end, int m0, int n0,
                                            char* lds, f32x4 acc[4][4]) {
  const int tid  = threadIdx.x;
  const int wave = tid >> 6;
  const int lane = tid & 63;
  const int wm = (wave & 1) << 6;
  const int wn = (wave >> 1) << 6;
  const int srow = tid >> 2;
  const int scol = ((tid & 3) ^ ((tid >> 3) & 3)) << 3;     // swizzled fetch chunk
  const int fm = lane & 15;
  const int fks = (((lane >> 4) ^ ((lane >> 1) & 3)) << 3); // swizzled read offset
  const f16_t* As = (const f16_t*)lds;
  const f16_t* Bs = (const f16_t*)(lds + 16384);
  char* ldsA = lds + (wave << 10);
  char* ldsB = lds + 16384 + (wave << 10);
  const f16_t* Ap0 = A + (size_t)(m0 + srow) * K + scol;
  const f16_t* Ap1 = A + (size_t)(m0 + 64 + srow) * K + scol;
  const f16_t* Bp0 = B + (size_t)(n0 + srow) * K + scol;
  const f16_t* Bp1 = B + (size_t)(n0 + 64 + srow) * K + scol;
  for (int k0 = 0; k0 < k_end; k0 += 64) {
    gload16(Ap0 + k0, ldsA);
    gload16(Ap1 + k0, ldsA + 4096);
    gload16(Ap0 + k0 + 32, ldsA + 8192);
    gload16(Ap1 + k0 + 32, ldsA + 12288);
    gload16(Bp0 + k0, ldsB);
    gload16(Bp1 + k0, ldsB + 4096);
    gload16(Bp0 + k0 + 32, ldsB + 8192);
    gload16(Bp1 + k0 + 32, ldsB + 12288);
    __syncthreads();
#pragma unroll
    for (int s = 0; s < 2; ++s) {
      const f16_t* As_s = As + (s << 12);
      const f16_t* Bs_s = Bs + (s << 12);
      half8 af[4], bfr[4];
#pragma unroll
      for (int i = 0; i < 4; ++i)
        af[i] = *(const half8*)(As_s + ((wm + i * 16 + fm) << 5) + fks);
#pragma unroll
      for (int j = 0; j < 4; ++j)
        bfr[j] = *(const half8*)(Bs_s + ((wn + j * 16 + fm) << 5) + fks);
#pragma unroll
      for (int i = 0; i < 4; ++i)
#pragma unroll
        for (int j = 0; j < 4; ++j)
          acc[i][j] = __builtin_amdgcn_mfma_f32_16x16x32_f16(af[i], bfr[j], acc[i][j], 0, 0, 0);
    }
    __syncthreads();
  }
}

// -- 8-wave 128m x 256n core, BK=64 (verified bit-exact in R7 run): waves
// 2m x 4n, 64x64 output each. LDS = 48 KB: A[2][128][32] @0, B[2][256][32]
// @16384. Same swizzle/fragment math as gemm_tile64.
__device__ __forceinline__ void gemm_tile64_w8(const f16_t* __restrict__ A,
                                               const f16_t* __restrict__ B,
                                               int K, int k_end, int m0, int n0,
                                               char* lds, f32x4 acc[4][4]) {
  const int tid  = threadIdx.x;            // 0..511
  const int wave = tid >> 6;
  const int lane = tid & 63;
  const int wm = (wave >> 2) << 6;         // 0,64
  const int wn = (wave & 3) << 6;          // 0,64,128,192
  const int srow = tid >> 2;               // 0..127
  const int scol = ((tid & 3) ^ ((tid >> 3) & 3)) << 3;     // swizzled fetch chunk
  const int fm = lane & 15;
  const int fks = (((lane >> 4) ^ ((lane >> 1) & 3)) << 3); // swizzled read offset
  const f16_t* As = (const f16_t*)lds;
  const f16_t* Bs = (const f16_t*)(lds + 16384);
  char* ldsAw = lds + (wave << 10);
  char* ldsBw = lds + 16384 + (wave << 10);
  const f16_t* Ap  = A + (size_t)(m0 + srow) * K + scol;
  const f16_t* Bp0 = B + (size_t)(n0 + srow) * K + scol;
  const f16_t* Bp1 = B + (size_t)(n0 + 128 + srow) * K + scol;
  for (int k0 = 0; k0 < k_end; k0 += 64) {
    gload16(Ap + k0, ldsAw);                 // A rows 0-127, k sub0
    gload16(Ap + k0 + 32, ldsAw + 8192);     // A sub1
    gload16(Bp0 + k0, ldsBw);                // B rows 0-127, sub0
    gload16(Bp1 + k0, ldsBw + 8192);         // B rows 128-255, sub0
    gload16(Bp0 + k0 + 32, ldsBw + 16384);   // B rows 0-127, sub1
    gload16(Bp1 + k0 + 32, ldsBw + 24576);   // B rows 128-255, sub1
    __syncthreads();
#pragma unroll
    for (int s = 0; s < 2; ++s) {
      const f16_t* As_s = As + (s << 12);    // 8KB sub
      const f16_t* Bs_s = Bs + (s << 13);    // 16KB sub
      half8 af[4], bfr[4];
#pragma unroll
      for (int i = 0; i < 4; ++i)
        af[i] = *(const half8*)(As_s + ((wm + i * 16 + fm) << 5) + fks);
#pragma unroll
      for (int j = 0; j < 4; ++j)
        bfr[j] = *(const half8*)(Bs_s + ((wn + j * 16 + fm) << 5) + fks);
#pragma unroll
      for (int i = 0; i < 4; ++i)
#pragma unroll
        for (int j = 0; j < 4; ++j)
          acc[i][j] = __builtin_amdgcn_mfma_f32_16x16x32_f16(af[i], bfr[j], acc[i][j], 0, 0, 0);
    }
    __syncthreads();
  }
}

// =================== 256x256 8-phase GEMM core (k_proj) =====================
// R3/R4: FETCH 203->74 MB via XCD swizzle, time pinned ~110-120us at
// 1 block/CU (128 KB LDS). Parked at structural ceiling.

#define P_BAR  __builtin_amdgcn_s_barrier()
#define P_SB   __builtin_amdgcn_sched_barrier(0)
#define P_WL   asm volatile("s_waitcnt lgkmcnt(0)" ::: "memory")
#define P_WL8  asm volatile("s_waitcnt lgkmcnt(8)" ::: "memory")
#define P_WV4  asm volatile("s_waitcnt vmcnt(4)" ::: "memory")
#define P_WV0  asm volatile("s_waitcnt vmcnt(0)" ::: "memory")
#define P_HI   __builtin_amdgcn_s_setprio(1)
#define P_LO   __builtin_amdgcn_s_setprio(0)

#define STAGE_A(buf, h, kt) do { if ((kt) < NT) {                          \
    const f16_t* g_ = Ag + (size_t)((h) * 128) * KD + (kt) * 64;           \
    char* d_ = ldsAw + (buf) * 65536 + (h) * 16384;                        \
    gload16(g_, d_); gload16(g_ + (size_t)64 * KD, d_ + 8192); } } while (0)

#define STAGE_B(buf, h, kt) do { if ((kt) < NT) {                          \
    const f16_t* g_ = Bg + (size_t)((h) * 128) * KD + (kt) * 64;           \
    char* d_ = ldsBw + (buf) * 65536 + (h) * 16384;                        \
    gload16(g_, d_); gload16(g_ + (size_t)64 * KD, d_ + 8192); } } while (0)

#define LDA8(mh, buf) do {                                                 \
    const char* p_ = ldsAr + (buf) * 65536 + (mh) * 8192;                  \
    _Pragma("unroll")                                                      \
    for (int i_ = 0; i_ < 4; ++i_) {                                       \
      af[i_][0] = *(const half8*)(p_ + (i_ << 11) + u0);                   \
      af[i_][1] = *(const half8*)(p_ + (i_ << 11) + u1); } } while (0)

#define LDB4(nh, buf) do {                                                 \
    const char* p_ = ldsBr + (buf) * 65536 + (nh) * 4096;                  \
    _Pragma("unroll")                                                      \
    for (int j_ = 0; j_ < 2; ++j_) {                                       \
      bf[nh][j_][0] = *(const half8*)(p_ + (j_ << 11) + u0);               \
      bf[nh][j_][1] = *(const half8*)(p_ + (j_ << 11) + u1); } } while (0)

#define MMQ(mh, nh) do {                                                   \
    _Pragma("unroll")                                                      \
    for (int i_ = 0; i_ < 4; ++i_)                                         \
    _Pragma("unroll")                                                      \
    for (int j_ = 0; j_ < 2; ++j_) {                                       \
      acc[(mh) * 4 + i_][(nh) * 2 + j_] =                                  \
        __builtin_amdgcn_mfma_f32_16x16x32_f16(af[i_][0], bf[nh][j_][0],   \
            acc[(mh) * 4 + i_][(nh) * 2 + j_], 0, 0, 0);                   \
      acc[(mh) * 4 + i_][(nh) * 2 + j_] =                                  \
        __builtin_amdgcn_mfma_f32_16x16x32_f16(af[i_][1], bf[nh][j_][1],   \
            acc[(mh) * 4 + i_][(nh) * 2 + j_], 0, 0, 0); } } while (0)

#define ITER_BODY(kt1, kt2, kt3, WAIT4) do {                               \
    /* ph1 */                                                              \
    LDA8(0, 0); LDB4(0, 0);                                                \
    STAGE_A(1, 0, kt1);                                                    \
    P_WL8; P_SB; P_BAR;                                                    \
    P_WL; P_SB;                                                            \
    P_HI; MMQ(0, 0); P_LO; P_SB;                                           \
    P_BAR;                                                                 \
    /* ph2 */                                                              \
    LDB4(1, 0);                                                            \
    STAGE_A(1, 1, kt1);                                                    \
    P_SB; P_BAR;                                                           \
    P_WL; P_SB;                                                            \
    P_HI; MMQ(0, 1); P_LO; P_SB;                                           \
    P_BAR;                                                                 \
    /* ph3 */                                                              \
    LDA8(1, 0);                                                            \
    STAGE_B(0, 0, kt2);                                                    \
    P_SB; P_BAR;                                                           \
    P_WL; P_SB;                                                            \
    P_HI; MMQ(1, 0); P_LO; P_SB;                                           \
    P_BAR;                                                                 \
    /* ph4: guard K-tile kt1 */                                            \
    STAGE_B(0, 1, kt2);                                                    \
    WAIT4; P_SB; P_BAR; P_SB;                                              \
    P_HI; MMQ(1, 1); P_LO; P_SB;                                           \
    P_BAR;                                                                 \
    /* ph5: compute K-tile kt1 (buf1) */                                   \
    LDA8(0, 1); LDB4(0, 1);                                                \
    STAGE_A(0, 0, kt2);                                                    \
    P_WL8; P_SB; P_BAR;                                                    \
    P_WL; P_SB;                                                            \
    P_HI; MMQ(0, 0); P_LO; P_SB;                                           \
    P_BAR;                                                                 \
    /* ph6 */                                                              \
    LDB4(1, 1);                                                            \
    STAGE_A(0, 1, kt2);                                                    \
    P_SB; P_BAR;                                                           \
    P_WL; P_SB;                                                            \
    P_HI; MMQ(0, 1); P_LO; P_SB;                                           \
    P_BAR;                                                                 \
    /* ph7 */                                                              \
    LDA8(1, 1);                                                            \
    STAGE_B(1, 0, kt3);                                                    \
    P_SB; P_BAR;                                                           \
    P_WL; P_SB;                                                            \
    P_HI; MMQ(1, 0); P_LO; P_SB;                                           \
    P_BAR;                                                                 \
    /* ph8: guard K-tile kt2 */                                            \
    STAGE_B(1, 1, kt3);                                                    \
    WAIT4; P_SB; P_BAR; P_SB;                                              \
    P_HI; MMQ(1, 1); P_LO; P_SB;                                           \
    P_BAR;                                                                 \
  } while (0)

// Merged Q/K/V projection: 256^2 tile, 8-phase counted-vmcnt schedule.
__global__ __launch_bounds__(512, 2)
void k_proj(const f16_t* __restrict__ X,
            const f16_t* __restrict__ Wq, const f16_t* __restrict__ Wk,
            const f16_t* __restrict__ Wv,
            f16_t* __restrict__ Qo, f16_t* __restrict__ Ko,
            u16* __restrict__ Vt) {
  __shared__ char lds[131072];
  constexpr int KD = C_DIM;      // 1024
  constexpr int NT = KD / 64;    // 16 K-tiles, 8 iterations
  const int z = blockIdx.z;
  const f16_t* W = (z == 0) ? Wq : (z == 1) ? Wk : Wv;
  // XCD chunk swizzle: 4y x 8x tile chunk per XCD (A fetched once/z).
  const int lin = (blockIdx.y << 3) | blockIdx.x;   // 0..255
  const int t_sw = ((lin & 7) << 5) + (lin >> 3);   // chunk c -> tiles [32c,32c+32)
  const int m0 = (t_sw >> 3) << 8, n0 = (t_sw & 7) << 8;

  const int tid = threadIdx.x, wave = tid >> 6, lane = tid & 63;
  const int wm = wave >> 2, wn = wave & 3;
  // staging: lane writes LDS (row = base + lane>>3, unit = lane&7);
  // row&7 == lane>>3, so pre-swizzled global chunk = (lane&7)^(lane>>3).
  const int srow = (wave << 3) + (lane >> 3);
  const int scol = (((lane & 7) ^ (lane >> 3)) << 3);
  const f16_t* Ag = X + (size_t)(m0 + srow) * KD + scol;
  const f16_t* Bg = W + (size_t)(n0 + srow) * KD + scol;
  char* ldsAw = lds + (wave << 10);
  char* ldsBw = lds + 32768 + (wave << 10);
  // ds_read de-swizzle: row&7 == lane&7; want chunk ks*4+(lane>>4).
  const int u0 = (((lane >> 4) ^ (lane & 7)) << 4);
  const int u1 = u0 ^ 64;
  const char* ldsAr = lds + ((wm * 128 + (lane & 15)) << 7);
  const char* ldsBr = lds + 32768 + ((wn * 64 + (lane & 15)) << 7);

  f32x4 acc[8][4];
#pragma unroll
  for (int i = 0; i < 8; ++i)
#pragma unroll
    for (int j = 0; j < 4; ++j) acc[i][j] = (f32x4){0.f, 0.f, 0.f, 0.f};
  half8 af[4][2], bf[2][2][2];

  // prologue: K-tile 0 full + B of K-tile 1 (A of K-tile 1 staged at ph1/ph2)
  STAGE_A(0, 0, 0); STAGE_A(0, 1, 0);
  STAGE_B(0, 0, 0); STAGE_B(0, 1, 0);
  STAGE_B(1, 0, 1); STAGE_B(1, 1, 1);
  P_WV4;     // K-tile 0 landed; B(1) may stay in flight
  P_SB; P_BAR; P_SB;

  for (int I = 0; I < NT / 2 - 1; ++I) {
    const int kt1 = 2 * I + 1, kt2 = 2 * I + 2, kt3 = 2 * I + 3;
    ITER_BODY(kt1, kt2, kt3, P_WV4);
  }
  // peeled final iteration: kt2/kt3 >= NT (stages skipped) -> must drain to 0
  ITER_BODY(NT - 1, NT, NT + 1, P_WV0);

  // epilogue: C/D 16x16 layout (m89): col = lane&15, row = (lane>>4)*4 + reg
  const int mb = m0 + wm * 128 + ((lane >> 4) << 2);
  const int nb = n0 + wn * 64 + (lane & 15);
  if (z < 2) {
    f16_t* Cb = z ? Ko : Qo;
#pragma unroll
    for (int ii = 0; ii < 8; ++ii)
#pragma unroll
      for (int jj = 0; jj < 4; ++jj) {
        const size_t base = (size_t)(mb + ii * 16) * H_DIM + (nb + jj * 16);
#pragma unroll
        for (int r = 0; r < 4; ++r)
          Cb[base + (size_t)r * H_DIM] = (f16_t)acc[ii][jj][r];
      }
  } else {
    // Vt transposed store: 4 consecutive t per frag -> line-combined ushort4
#pragma unroll
    for (int ii = 0; ii < 8; ++ii) {
      const int gm = mb + ii * 16;          // b*T + t
      const int b = gm >> 11;
      const int t = gm & (T_SEQ - 1);
#pragma unroll
      for (int jj = 0; jj < 4; ++jj) {
        const int h = nb + jj * 16;
        ushort4 pk;
        pk.x = __builtin_bit_cast(u16, (f16_t)acc[ii][jj][0]);
        pk.y = __builtin_bit_cast(u16, (f16_t)acc[ii][jj][1]);
        pk.z = __builtin_bit_cast(u16, (f16_t)acc[ii][jj][2]);
        pk.w = __builtin_bit_cast(u16, (f16_t)acc[ii][jj][3]);
        *(ushort4*)(Vt + ((size_t)(b * H_DIM + h) * T_SEQ + t)) = pk;
      }
    }
  }
}

// C/D layout 16x16 (verified m89): col = lane&15, row = (lane>>4)*4 + reg
#define EPI_PREAMBLE                                            \
  const int lane = threadIdx.x & 63;                            \
  const int wl_e = (threadIdx.x >> 6) & 3;                      \
  const int mb = m0 + ((wl_e & 1) << 6) + ((lane >> 4) << 2);   \
  const int nb = n0 + ((wl_e >> 1) << 6) + (lane & 15);

#define ZERO_ACC                                                \
  f32x4 acc[4][4];                                              \
  _Pragma("unroll")                                             \
  for (int i = 0; i < 4; ++i)                                   \
    _Pragma("unroll")                                           \
    for (int j = 0; j < 4; ++j) acc[i][j] = (f32x4){0.f, 0.f, 0.f, 0.f};

// scores: lower-triangle tiles, 4-wave BK=64 core. R8: back to the R4 map
// (session-best 332 us): 17 consecutive triangle-tiles per XCD.
__global__ __launch_bounds__(256, 2)
void k_scores(const f16_t* __restrict__ Q, const f16_t* __restrict__ Kc,
              f16_t* __restrict__ S) {
  __shared__ char lds[32768];
  ZERO_ACC
  const int orig = blockIdx.x;             // 0..135
  const int p = (orig & 7) * 17 + (orig >> 3);
  int i = (int)((sqrtf(8.f * p + 1.f) - 1.f) * 0.5f);
  while ((i + 1) * (i + 2) / 2 <= p) ++i;
  while (i * (i + 1) / 2 > p) --i;
  const int j = p - i * (i + 1) / 2;
  const int b = blockIdx.y;
  const int m0 = i << 7, n0 = j << 7;
  const f16_t* Aq = Q + (size_t)b * T_SEQ * H_DIM;
  const f16_t* Bk = Kc + (size_t)b * T_SEQ * H_DIM;
  f16_t* Sb = S + (size_t)b * T_SEQ * T_SEQ;
  gemm_tile64(Aq, Bk, H_DIM, H_DIM, m0, n0, lds, acc);
  EPI_PREAMBLE
  const float scale = 0.022097086912079608f;  // 2048^-0.5
#pragma unroll
  for (int i2 = 0; i2 < 4; ++i2)
#pragma unroll
    for (int j2 = 0; j2 < 4; ++j2) {
      const size_t base = (size_t)(mb + i2 * 16) * T_SEQ + (nb + j2 * 16);
#pragma unroll
      for (int r = 0; r < 4; ++r)
        Sb[base + (size_t)r * T_SEQ] = (f16_t)(acc[i2][j2][r] * scale);
    }
}

// causal softmax: one row/block, one half8/thread, exp kept in registers.
// Writes zeros only up to n128 = ceil(n/128)*128 — exactly the region PV reads.
__global__ __launch_bounds__(256)
void k_softmax(const f16_t* __restrict__ S, f16_t* __restrict__ P) {
  const int row = blockIdx.x;              // b*T + t
  const int t = row & (T_SEQ - 1);
  const int n = t + 1;
  const int n128 = (n + 127) & ~127;
  const int tid = threadIdx.x;
  const int c0 = tid << 3;
  const f16_t* s = S + (size_t)row * T_SEQ;
  f16_t* p = P + (size_t)row * T_SEQ;
  __shared__ float red[8];
  half8 v;
  float lmax = -3.0e38f;
  if (c0 < n) {
    v = *(const half8*)(s + c0);
#pragma unroll
    for (int r = 0; r < 8; ++r)
      if (c0 + r < n) lmax = fmaxf(lmax, (float)v[r]);
  }
#pragma unroll
  for (int off = 32; off > 0; off >>= 1) lmax = fmaxf(lmax, __shfl_xor(lmax, off, 64));
  if ((tid & 63) == 0) red[tid >> 6] = lmax;
  __syncthreads();
  const float m = fmaxf(fmaxf(red[0], red[1]), fmaxf(red[2], red[3]));
  float e[8];
  float lsum = 0.f;
  if (c0 < n) {
#pragma unroll
    for (int r = 0; r < 8; ++r) {
      e[r] = (c0 + r < n) ? __expf((float)v[r] - m) : 0.f;
      lsum += e[r];
    }
  }
#pragma unroll
  for (int off = 32; off > 0; off >>= 1) lsum += __shfl_xor(lsum, off, 64);
  if ((tid & 63) == 0) red[4 + (tid >> 6)] = lsum;
  __syncthreads();
  const float inv = 1.0f / (red[4] + red[5] + red[6] + red[7]);
  if (c0 < n128) {
    half8 o;
#pragma unroll
    for (int r = 0; r < 8; ++r)
      o[r] = (c0 + r < n) ? (f16_t)(e[r] * inv) : (f16_t)0.f;
    *(half8*)(p + c0) = o;
  }
}

// PV, R8: w8 128m x 256n core, UNPAIRED grid (8 n256, 16 m, 4 b) = 512
// blocks (2/CU balanced — R7's 256-block grid was 1/CU, staging latency
// exposed). Big-K first: y=0 -> mi=15, so long blocks schedule first.
// XCD = n256-col (lin%8 = x): per XCD one Vt panel (256 rows x 2048 x 2B
// x 4b = 4 MB) = L2-resident, reused by 64 blocks; A(P) streams once per
// block with half the staging count of the 128n tile.
// Row t in m-tile mi has n128 == (mi+1)*128 exactly -> k_end = m0+128
// covers precisely the region softmax wrote (no garbage reads).
__global__ __launch_bounds__(512, 2)
void k_pv(const f16_t* __restrict__ P, const f16_t* __restrict__ Vt,
          float* __restrict__ Out) {
  __shared__ char lds[49152];
  const int b = blockIdx.z;
  const int n0 = blockIdx.x << 8;          // 0..7 -> 256-wide n-tile
  const int mi = 15 - blockIdx.y;          // big K first
  const int m0 = mi << 7;
  const f16_t* Ap = P + (size_t)b * T_SEQ * T_SEQ;
  const f16_t* Bv = Vt + (size_t)b * H_DIM * T_SEQ;
  float* Ob = Out + (size_t)b * T_SEQ * H_DIM;
  const int lane = threadIdx.x & 63;
  const int wave = threadIdx.x >> 6;
  const int wm = (wave >> 2) << 6;
  const int wn = (wave & 3) << 6;
  ZERO_ACC
  gemm_tile64_w8(Ap, Bv, T_SEQ, m0 + 128, m0, n0, lds, acc);
  const int mb = m0 + wm + ((lane >> 4) << 2);
  const int nb = n0 + wn + (lane & 15);
#pragma unroll
  for (int i = 0; i < 4; ++i)
#pragma unroll
    for (int j = 0; j < 4; ++j) {
      const size_t base = (size_t)(mb + i * 16) * H_DIM + (nb + j * 16);
#pragma unroll
      for (int r = 0; r < 4; ++r)
        Ob[base + (size_t)r * H_DIM] = acc[i][j][r];
    }
}

// one fused f32 -> f16 conversion pass over x, Wk, Wq, Wv
#define XN4 ((B_SZ * T_SEQ * C_DIM) / 4)   // 2097152
#define WN4 ((H_DIM * C_DIM) / 4)          // 524288
__global__ __launch_bounds__(256)
void k_cvt_all(const float4* __restrict__ x,  const float4* __restrict__ wk,
               const float4* __restrict__ wq, const float4* __restrict__ wv,
               ushort4* __restrict__ xb, ushort4* __restrict__ wkb,
               ushort4* __restrict__ wqb, ushort4* __restrict__ wvb) {
  int idx = blockIdx.x * 256 + threadIdx.x;
  const float4* src; ushort4* dst;
  if (idx < XN4)                { src = x;  dst = xb; }
  else if (idx < XN4 + WN4)     { src = wk; dst = wkb; idx -= XN4; }
  else if (idx < XN4 + 2 * WN4) { src = wq; dst = wqb; idx -= XN4 + WN4; }
  else                          { src = wv; dst = wvb; idx -= XN4 + 2 * WN4; }
  const float4 v = src[idx];
  ushort4 o;
  o.x = __builtin_bit_cast(u16, (f16_t)v.x);
  o.y = __builtin_bit_cast(u16, (f16_t)v.y);
  o.z = __builtin_bit_cast(u16, (f16_t)v.z);
  o.w = __builtin_bit_cast(u16, (f16_t)v.w);
  dst[idx] = o;
}

extern "C" void kernel_launch(void* const* d_in, const int* in_sizes, int n_in,
                              void* d_out, int out_size, void* d_ws, size_t ws_size,
                              hipStream_t stream) {
  (void)in_sizes; (void)n_in; (void)out_size; (void)ws_size;
  const float* x  = (const float*)d_in[0];
  const float* Wk = (const float*)d_in[1];
  const float* Wq = (const float*)d_in[2];
  const float* Wv = (const float*)d_in[3];
  float* out = (float*)d_out;
  char* ws = (char*)d_ws;
  // workspace (192 MB):
  //  [0,32M) q f16   [32M,64M) k f16   [64M,96M) Vt f16 [B,H,T]
  //  [96M,128M) S f16 [B,T,T]          [160M,192M) P f16
  //  cvt temps (dead before S written): xb@96M, wk@128M, wq@132M, wv@136M
  f16_t* qb  = (f16_t*)(ws);
  f16_t* kb  = (f16_t*)(ws + (32ull << 20));
  f16_t* vt  = (f16_t*)(ws + (64ull << 20));
  f16_t* S   = (f16_t*)(ws + (96ull << 20));
  f16_t* P   = (f16_t*)(ws + (160ull << 20));
  f16_t* xb  = (f16_t*)(ws + (96ull << 20));
  f16_t* wkb = (f16_t*)(ws + (128ull << 20));
  f16_t* wqb = (f16_t*)(ws + (132ull << 20));
  f16_t* wvb = (f16_t*)(ws + (136ull << 20));

  k_cvt_all<<<(XN4 + 3 * WN4) / 256, 256, 0, stream>>>(
      (const float4*)x, (const float4*)Wk, (const float4*)Wq, (const float4*)Wv,
      (ushort4*)xb, (ushort4*)wkb, (ushort4*)wqb, (ushort4*)wvb);

  dim3 gp(H_DIM / 256, (B_SZ * T_SEQ) / 256, 3);       // 8 x 32 x 3
  k_proj<<<gp, 512, 0, stream>>>(xb, wqb, wkb, wvb, qb, kb, (u16*)vt);

  dim3 gs(136, B_SZ);                                   // lower-triangle tiles
  k_scores<<<gs, 256, 0, stream>>>(qb, kb, S);
  k_softmax<<<B_SZ * T_SEQ, 256, 0, stream>>>(S, P);
  dim3 gv(H_DIM / 256, T_SEQ / 128, B_SZ);              // 8 x 16 x 4, big-K first
  k_pv<<<gv, 512, 0, stream>>>(P, vt, out);
}

// Round 9
// 327.483 us; speedup vs baseline: 1.0539x; 1.0425x over previous
//
#include <hip/hip_runtime.h>
#include <math.h>

typedef _Float16 f16_t;
typedef _Float16 half8 __attribute__((ext_vector_type(8)));
typedef float f32x4 __attribute__((ext_vector_type(4)));
typedef unsigned short u16;

#define T_SEQ 2048
#define H_DIM 2048
#define C_DIM 1024
#define B_SZ  4

// async global->LDS, 16B per lane. LDS dest = wave-uniform base + lane*16.
__device__ __forceinline__ void gload16(const void* g, void* l) {
  typedef const __attribute__((address_space(1))) unsigned int* gp_t;
  typedef __attribute__((address_space(3))) unsigned int* lp_t;
  __builtin_amdgcn_global_load_lds((gp_t)(unsigned long long)g,
                                   (lp_t)(unsigned int)(unsigned long long)l,
                                   16, 0, 0);
}

// -- 4-wave 16x16 core, BK=64 (2 sub-buffers, ONE barrier pair per 64-K) --
// LDS = 32 KB: A[2][128][32] f16 @0, B[2][128][32] f16 @16384.
// Session conclusion (R4-R8): this core + the R4 grid maps is the empirical
// optimum of the decomposition; all neighborhood moves (w8 wide tile, sk2,
// occupancy 4, qp/2D XCD maps) regressed 4-13 us. Attention is bound by
// panel re-streaming at L3 rate (per-batch panels 8 MB > 4 MB L2/XCD).
__device__ __forceinline__ void gemm_tile64(const f16_t* __restrict__ A,
                                            const f16_t* __restrict__ B,
                                            int K, int k_end, int m0, int n0,
                                            char* lds, f32x4 acc[4][4]) {
  const int tid  = threadIdx.x;
  const int wave = tid >> 6;
  const int lane = tid & 63;
  const int wm = (wave & 1) << 6;
  const int wn = (wave >> 1) << 6;
  const int srow = tid >> 2;
  const int scol = ((tid & 3) ^ ((tid >> 3) & 3)) << 3;     // swizzled fetch chunk
  const int fm = lane & 15;
  const int fks = (((lane >> 4) ^ ((lane >> 1) & 3)) << 3); // swizzled read offset
  const f16_t* As = (const f16_t*)lds;
  const f16_t* Bs = (const f16_t*)(lds + 16384);
  char* ldsA = lds + (wave << 10);
  char* ldsB = lds + 16384 + (wave << 10);
  const f16_t* Ap0 = A + (size_t)(m0 + srow) * K + scol;
  const f16_t* Ap1 = A + (size_t)(m0 + 64 + srow) * K + scol;
  const f16_t* Bp0 = B + (size_t)(n0 + srow) * K + scol;
  const f16_t* Bp1 = B + (size_t)(n0 + 64 + srow) * K + scol;
  for (int k0 = 0; k0 < k_end; k0 += 64) {
    gload16(Ap0 + k0, ldsA);
    gload16(Ap1 + k0, ldsA + 4096);
    gload16(Ap0 + k0 + 32, ldsA + 8192);
    gload16(Ap1 + k0 + 32, ldsA + 12288);
    gload16(Bp0 + k0, ldsB);
    gload16(Bp1 + k0, ldsB + 4096);
    gload16(Bp0 + k0 + 32, ldsB + 8192);
    gload16(Bp1 + k0 + 32, ldsB + 12288);
    __syncthreads();
#pragma unroll
    for (int s = 0; s < 2; ++s) {
      const f16_t* As_s = As + (s << 12);
      const f16_t* Bs_s = Bs + (s << 12);
      half8 af[4], bfr[4];
#pragma unroll
      for (int i = 0; i < 4; ++i)
        af[i] = *(const half8*)(As_s + ((wm + i * 16 + fm) << 5) + fks);
#pragma unroll
      for (int j = 0; j < 4; ++j)
        bfr[j] = *(const half8*)(Bs_s + ((wn + j * 16 + fm) << 5) + fks);
#pragma unroll
      for (int i = 0; i < 4; ++i)
#pragma unroll
        for (int j = 0; j < 4; ++j)
          acc[i][j] = __builtin_amdgcn_mfma_f32_16x16x32_f16(af[i], bfr[j], acc[i][j], 0, 0, 0);
    }
    __syncthreads();
  }
}

// =================== 256x256 8-phase GEMM core (k_proj) =====================
// R3 post-mortem: FETCH 203->74 MB (XCD swizzle) but time flat ~111us; three
// schedules tie -> phase windows serialize LDS-read vs MFMA at 1 block/CU.
// Parked at its structural ceiling (~880 TF).

#define P_BAR  __builtin_amdgcn_s_barrier()
#define P_SB   __builtin_amdgcn_sched_barrier(0)
#define P_WL   asm volatile("s_waitcnt lgkmcnt(0)" ::: "memory")
#define P_WL8  asm volatile("s_waitcnt lgkmcnt(8)" ::: "memory")
#define P_WV4  asm volatile("s_waitcnt vmcnt(4)" ::: "memory")
#define P_WV0  asm volatile("s_waitcnt vmcnt(0)" ::: "memory")
#define P_HI   __builtin_amdgcn_s_setprio(1)
#define P_LO   __builtin_amdgcn_s_setprio(0)

#define STAGE_A(buf, h, kt) do { if ((kt) < NT) {                          \
    const f16_t* g_ = Ag + (size_t)((h) * 128) * KD + (kt) * 64;           \
    char* d_ = ldsAw + (buf) * 65536 + (h) * 16384;                        \
    gload16(g_, d_); gload16(g_ + (size_t)64 * KD, d_ + 8192); } } while (0)

#define STAGE_B(buf, h, kt) do { if ((kt) < NT) {                          \
    const f16_t* g_ = Bg + (size_t)((h) * 128) * KD + (kt) * 64;           \
    char* d_ = ldsBw + (buf) * 65536 + (h) * 16384;                        \
    gload16(g_, d_); gload16(g_ + (size_t)64 * KD, d_ + 8192); } } while (0)

#define LDA8(mh, buf) do {                                                 \
    const char* p_ = ldsAr + (buf) * 65536 + (mh) * 8192;                  \
    _Pragma("unroll")                                                      \
    for (int i_ = 0; i_ < 4; ++i_) {                                       \
      af[i_][0] = *(const half8*)(p_ + (i_ << 11) + u0);                   \
      af[i_][1] = *(const half8*)(p_ + (i_ << 11) + u1); } } while (0)

#define LDB4(nh, buf) do {                                                 \
    const char* p_ = ldsBr + (buf) * 65536 + (nh) * 4096;                  \
    _Pragma("unroll")                                                      \
    for (int j_ = 0; j_ < 2; ++j_) {                                       \
      bf[nh][j_][0] = *(const half8*)(p_ + (j_ << 11) + u0);               \
      bf[nh][j_][1] = *(const half8*)(p_ + (j_ << 11) + u1); } } while (0)

#define MMQ(mh, nh) do {                                                   \
    _Pragma("unroll")                                                      \
    for (int i_ = 0; i_ < 4; ++i_)                                         \
    _Pragma("unroll")                                                      \
    for (int j_ = 0; j_ < 2; ++j_) {                                       \
      acc[(mh) * 4 + i_][(nh) * 2 + j_] =                                  \
        __builtin_amdgcn_mfma_f32_16x16x32_f16(af[i_][0], bf[nh][j_][0],   \
            acc[(mh) * 4 + i_][(nh) * 2 + j_], 0, 0, 0);                   \
      acc[(mh) * 4 + i_][(nh) * 2 + j_] =                                  \
        __builtin_amdgcn_mfma_f32_16x16x32_f16(af[i_][1], bf[nh][j_][1],   \
            acc[(mh) * 4 + i_][(nh) * 2 + j_], 0, 0, 0); } } while (0)

#define ITER_BODY(kt1, kt2, kt3, WAIT4) do {                               \
    /* ph1 */                                                              \
    LDA8(0, 0); LDB4(0, 0);                                                \
    STAGE_A(1, 0, kt1);                                                    \
    P_WL8; P_SB; P_BAR;                                                    \
    P_WL; P_SB;                                                            \
    P_HI; MMQ(0, 0); P_LO; P_SB;                                           \
    P_BAR;                                                                 \
    /* ph2 */                                                              \
    LDB4(1, 0);                                                            \
    STAGE_A(1, 1, kt1);                                                    \
    P_SB; P_BAR;                                                           \
    P_WL; P_SB;                                                            \
    P_HI; MMQ(0, 1); P_LO; P_SB;                                           \
    P_BAR;                                                                 \
    /* ph3 */                                                              \
    LDA8(1, 0);                                                            \
    STAGE_B(0, 0, kt2);                                                    \
    P_SB; P_BAR;                                                           \
    P_WL; P_SB;                                                            \
    P_HI; MMQ(1, 0); P_LO; P_SB;                                           \
    P_BAR;                                                                 \
    /* ph4: guard K-tile kt1 */                                            \
    STAGE_B(0, 1, kt2);                                                    \
    WAIT4; P_SB; P_BAR; P_SB;                                              \
    P_HI; MMQ(1, 1); P_LO; P_SB;                                           \
    P_BAR;                                                                 \
    /* ph5: compute K-tile kt1 (buf1) */                                   \
    LDA8(0, 1); LDB4(0, 1);                                                \
    STAGE_A(0, 0, kt2);                                                    \
    P_WL8; P_SB; P_BAR;                                                    \
    P_WL; P_SB;                                                            \
    P_HI; MMQ(0, 0); P_LO; P_SB;                                           \
    P_BAR;                                                                 \
    /* ph6 */                                                              \
    LDB4(1, 1);                                                            \
    STAGE_A(0, 1, kt2);                                                    \
    P_SB; P_BAR;                                                           \
    P_WL; P_SB;                                                            \
    P_HI; MMQ(0, 1); P_LO; P_SB;                                           \
    P_BAR;                                                                 \
    /* ph7 */                                                              \
    LDA8(1, 1);                                                            \
    STAGE_B(1, 0, kt3);                                                    \
    P_SB; P_BAR;                                                           \
    P_WL; P_SB;                                                            \
    P_HI; MMQ(1, 0); P_LO; P_SB;                                           \
    P_BAR;                                                                 \
    /* ph8: guard K-tile kt2 */                                            \
    STAGE_B(1, 1, kt3);                                                    \
    WAIT4; P_SB; P_BAR; P_SB;                                              \
    P_HI; MMQ(1, 1); P_LO; P_SB;                                           \
    P_BAR;                                                                 \
  } while (0)

// Merged Q/K/V projection: 256^2 tile, 8-phase counted-vmcnt schedule.
__global__ __launch_bounds__(512, 2)
void k_proj(const f16_t* __restrict__ X,
            const f16_t* __restrict__ Wq, const f16_t* __restrict__ Wk,
            const f16_t* __restrict__ Wv,
            f16_t* __restrict__ Qo, f16_t* __restrict__ Ko,
            u16* __restrict__ Vt) {
  __shared__ char lds[131072];
  constexpr int KD = C_DIM;      // 1024
  constexpr int NT = KD / 64;    // 16 K-tiles, 8 iterations
  const int z = blockIdx.z;
  const f16_t* W = (z == 0) ? Wq : (z == 1) ? Wk : Wv;
  // XCD chunk swizzle: 4y x 8x tile chunk per XCD (A fetched once/z).
  const int lin = (blockIdx.y << 3) | blockIdx.x;   // 0..255
  const int t_sw = ((lin & 7) << 5) + (lin >> 3);   // chunk c -> tiles [32c,32c+32)
  const int m0 = (t_sw >> 3) << 8, n0 = (t_sw & 7) << 8;

  const int tid = threadIdx.x, wave = tid >> 6, lane = tid & 63;
  const int wm = wave >> 2, wn = wave & 3;
  // staging: lane writes LDS (row = base + lane>>3, unit = lane&7);
  // row&7 == lane>>3, so pre-swizzled global chunk = (lane&7)^(lane>>3).
  const int srow = (wave << 3) + (lane >> 3);
  const int scol = (((lane & 7) ^ (lane >> 3)) << 3);
  const f16_t* Ag = X + (size_t)(m0 + srow) * KD + scol;
  const f16_t* Bg = W + (size_t)(n0 + srow) * KD + scol;
  char* ldsAw = lds + (wave << 10);
  char* ldsBw = lds + 32768 + (wave << 10);
  // ds_read de-swizzle: row&7 == lane&7; want chunk ks*4+(lane>>4).
  const int u0 = (((lane >> 4) ^ (lane & 7)) << 4);
  const int u1 = u0 ^ 64;
  const char* ldsAr = lds + ((wm * 128 + (lane & 15)) << 7);
  const char* ldsBr = lds + 32768 + ((wn * 64 + (lane & 15)) << 7);

  f32x4 acc[8][4];
#pragma unroll
  for (int i = 0; i < 8; ++i)
#pragma unroll
    for (int j = 0; j < 4; ++j) acc[i][j] = (f32x4){0.f, 0.f, 0.f, 0.f};
  half8 af[4][2], bf[2][2][2];

  // prologue: K-tile 0 full + B of K-tile 1 (A of K-tile 1 staged at ph1/ph2)
  STAGE_A(0, 0, 0); STAGE_A(0, 1, 0);
  STAGE_B(0, 0, 0); STAGE_B(0, 1, 0);
  STAGE_B(1, 0, 1); STAGE_B(1, 1, 1);
  P_WV4;     // K-tile 0 landed; B(1) may stay in flight
  P_SB; P_BAR; P_SB;

  for (int I = 0; I < NT / 2 - 1; ++I) {
    const int kt1 = 2 * I + 1, kt2 = 2 * I + 2, kt3 = 2 * I + 3;
    ITER_BODY(kt1, kt2, kt3, P_WV4);
  }
  // peeled final iteration: kt2/kt3 >= NT (stages skipped) -> must drain to 0
  ITER_BODY(NT - 1, NT, NT + 1, P_WV0);

  // epilogue: C/D 16x16 layout (m89): col = lane&15, row = (lane>>4)*4 + reg
  const int mb = m0 + wm * 128 + ((lane >> 4) << 2);
  const int nb = n0 + wn * 64 + (lane & 15);
  if (z < 2) {
    f16_t* Cb = z ? Ko : Qo;
#pragma unroll
    for (int ii = 0; ii < 8; ++ii)
#pragma unroll
      for (int jj = 0; jj < 4; ++jj) {
        const size_t base = (size_t)(mb + ii * 16) * H_DIM + (nb + jj * 16);
#pragma unroll
        for (int r = 0; r < 4; ++r)
          Cb[base + (size_t)r * H_DIM] = (f16_t)acc[ii][jj][r];
      }
  } else {
    // Vt transposed store: 4 consecutive t per frag -> line-combined ushort4
#pragma unroll
    for (int ii = 0; ii < 8; ++ii) {
      const int gm = mb + ii * 16;          // b*T + t
      const int b = gm >> 11;
      const int t = gm & (T_SEQ - 1);
#pragma unroll
      for (int jj = 0; jj < 4; ++jj) {
        const int h = nb + jj * 16;
        ushort4 pk;
        pk.x = __builtin_bit_cast(u16, (f16_t)acc[ii][jj][0]);
        pk.y = __builtin_bit_cast(u16, (f16_t)acc[ii][jj][1]);
        pk.z = __builtin_bit_cast(u16, (f16_t)acc[ii][jj][2]);
        pk.w = __builtin_bit_cast(u16, (f16_t)acc[ii][jj][3]);
        *(ushort4*)(Vt + ((size_t)(b * H_DIM + h) * T_SEQ + t)) = pk;
      }
    }
  }
}

// C/D layout 16x16 (verified m89): col = lane&15, row = (lane>>4)*4 + reg
#define EPI_PREAMBLE                                            \
  const int lane = threadIdx.x & 63;                            \
  const int wl_e = (threadIdx.x >> 6) & 3;                      \
  const int mb = m0 + ((wl_e & 1) << 6) + ((lane >> 4) << 2);   \
  const int nb = n0 + ((wl_e >> 1) << 6) + (lane & 15);

#define ZERO_ACC                                                \
  f32x4 acc[4][4];                                              \
  _Pragma("unroll")                                             \
  for (int i = 0; i < 4; ++i)                                   \
    _Pragma("unroll")                                           \
    for (int j = 0; j < 4; ++j) acc[i][j] = (f32x4){0.f, 0.f, 0.f, 0.f};

// scores: lower-triangle tiles only, 4-wave BK=64 core (R4 config).
// XCD chunk swizzle: 136 = 8 x 17 -> 17 consecutive triangle-tiles per XCD.
__global__ __launch_bounds__(256, 2)
void k_scores(const f16_t* __restrict__ Q, const f16_t* __restrict__ Kc,
              f16_t* __restrict__ S) {
  __shared__ char lds[32768];
  ZERO_ACC
  const int orig = blockIdx.x;             // 0..135
  const int p = (orig & 7) * 17 + (orig >> 3);
  int i = (int)((sqrtf(8.f * p + 1.f) - 1.f) * 0.5f);
  while ((i + 1) * (i + 2) / 2 <= p) ++i;
  while (i * (i + 1) / 2 > p) --i;
  const int j = p - i * (i + 1) / 2;
  const int b = blockIdx.y;
  const int m0 = i << 7, n0 = j << 7;
  const f16_t* Aq = Q + (size_t)b * T_SEQ * H_DIM;
  const f16_t* Bk = Kc + (size_t)b * T_SEQ * H_DIM;
  f16_t* Sb = S + (size_t)b * T_SEQ * T_SEQ;
  gemm_tile64(Aq, Bk, H_DIM, H_DIM, m0, n0, lds, acc);
  EPI_PREAMBLE
  const float scale = 0.022097086912079608f;  // 2048^-0.5
#pragma unroll
  for (int i2 = 0; i2 < 4; ++i2)
#pragma unroll
    for (int j2 = 0; j2 < 4; ++j2) {
      const size_t base = (size_t)(mb + i2 * 16) * T_SEQ + (nb + j2 * 16);
#pragma unroll
      for (int r = 0; r < 4; ++r)
        Sb[base + (size_t)r * T_SEQ] = (f16_t)(acc[i2][j2][r] * scale);
    }
}

// causal softmax: one row/block, one half8/thread, exp kept in registers.
// Writes zeros only up to n128 = ceil(n/128)*128 — exactly the region PV reads.
__global__ __launch_bounds__(256)
void k_softmax(const f16_t* __restrict__ S, f16_t* __restrict__ P) {
  const int row = blockIdx.x;              // b*T + t
  const int t = row & (T_SEQ - 1);
  const int n = t + 1;
  const int n128 = (n + 127) & ~127;
  const int tid = threadIdx.x;
  const int c0 = tid << 3;
  const f16_t* s = S + (size_t)row * T_SEQ;
  f16_t* p = P + (size_t)row * T_SEQ;
  __shared__ float red[8];
  half8 v;
  float lmax = -3.0e38f;
  if (c0 < n) {
    v = *(const half8*)(s + c0);
#pragma unroll
    for (int r = 0; r < 8; ++r)
      if (c0 + r < n) lmax = fmaxf(lmax, (float)v[r]);
  }
#pragma unroll
  for (int off = 32; off > 0; off >>= 1) lmax = fmaxf(lmax, __shfl_xor(lmax, off, 64));
  if ((tid & 63) == 0) red[tid >> 6] = lmax;
  __syncthreads();
  const float m = fmaxf(fmaxf(red[0], red[1]), fmaxf(red[2], red[3]));
  float e[8];
  float lsum = 0.f;
  if (c0 < n) {
#pragma unroll
    for (int r = 0; r < 8; ++r) {
      e[r] = (c0 + r < n) ? __expf((float)v[r] - m) : 0.f;
      lsum += e[r];
    }
  }
#pragma unroll
  for (int off = 32; off > 0; off >>= 1) lsum += __shfl_xor(lsum, off, 64);
  if ((tid & 63) == 0) red[4 + (tid >> 6)] = lsum;
  __syncthreads();
  const float inv = 1.0f / (red[4] + red[5] + red[6] + red[7]);
  if (c0 < n128) {
    half8 o;
#pragma unroll
    for (int r = 0; r < 8; ++r)
      o[r] = (c0 + r < n) ? (f16_t)(e[r] * inv) : (f16_t)0.f;
    *(half8*)(p + c0) = o;
  }
}

// PV with diagonal pairing (R4 config, session-best): block (n, q, b)
// computes m-tiles 15-q and q (uniform 17 tile-units of K per block;
// grid = 512 = one balanced round at 2 blocks/CU). 4-wave BK=64 core.
__global__ __launch_bounds__(256, 2)
void k_pv(const f16_t* __restrict__ P, const f16_t* __restrict__ Vt,
          float* __restrict__ Out) {
  __shared__ char lds[32768];
  const int b = blockIdx.z;
  const int n0 = blockIdx.x << 7;
  const f16_t* Ap = P + (size_t)b * T_SEQ * T_SEQ;
  const f16_t* Bv = Vt + (size_t)b * H_DIM * T_SEQ;
  float* Ob = Out + (size_t)b * T_SEQ * H_DIM;
#pragma unroll
  for (int u = 0; u < 2; ++u) {
    const int mi = u ? blockIdx.y : (15 - blockIdx.y);   // big K first
    const int m0 = mi << 7;
    ZERO_ACC
    gemm_tile64(Ap, Bv, T_SEQ, m0 + 128, m0, n0, lds, acc);
    EPI_PREAMBLE
#pragma unroll
    for (int i = 0; i < 4; ++i)
#pragma unroll
      for (int j = 0; j < 4; ++j) {
        const size_t base = (size_t)(mb + i * 16) * H_DIM + (nb + j * 16);
#pragma unroll
        for (int r = 0; r < 4; ++r)
          Ob[base + (size_t)r * H_DIM] = acc[i][j][r];
      }
    __syncthreads();   // LDS reuse barrier between the two m-tiles
  }
}

// one fused f32 -> f16 conversion pass over x, Wk, Wq, Wv
#define XN4 ((B_SZ * T_SEQ * C_DIM) / 4)   // 2097152
#define WN4 ((H_DIM * C_DIM) / 4)          // 524288
__global__ __launch_bounds__(256)
void k_cvt_all(const float4* __restrict__ x,  const float4* __restrict__ wk,
               const float4* __restrict__ wq, const float4* __restrict__ wv,
               ushort4* __restrict__ xb, ushort4* __restrict__ wkb,
               ushort4* __restrict__ wqb, ushort4* __restrict__ wvb) {
  int idx = blockIdx.x * 256 + threadIdx.x;
  const float4* src; ushort4* dst;
  if (idx < XN4)                { src = x;  dst = xb; }
  else if (idx < XN4 + WN4)     { src = wk; dst = wkb; idx -= XN4; }
  else if (idx < XN4 + 2 * WN4) { src = wq; dst = wqb; idx -= XN4 + WN4; }
  else                          { src = wv; dst = wvb; idx -= XN4 + 2 * WN4; }
  const float4 v = src[idx];
  ushort4 o;
  o.x = __builtin_bit_cast(u16, (f16_t)v.x);
  o.y = __builtin_bit_cast(u16, (f16_t)v.y);
  o.z = __builtin_bit_cast(u16, (f16_t)v.z);
  o.w = __builtin_bit_cast(u16, (f16_t)v.w);
  dst[idx] = o;
}

extern "C" void kernel_launch(void* const* d_in, const int* in_sizes, int n_in,
                              void* d_out, int out_size, void* d_ws, size_t ws_size,
                              hipStream_t stream) {
  (void)in_sizes; (void)n_in; (void)out_size; (void)ws_size;
  const float* x  = (const float*)d_in[0];
  const float* Wk = (const float*)d_in[1];
  const float* Wq = (const float*)d_in[2];
  const float* Wv = (const float*)d_in[3];
  float* out = (float*)d_out;
  char* ws = (char*)d_ws;
  // workspace (192 MB):
  //  [0,32M) q f16   [32M,64M) k f16   [64M,96M) Vt f16 [B,H,T]
  //  [96M,128M) S f16 [B,T,T]          [160M,192M) P f16
  //  cvt temps (dead before S written): xb@96M, wk@128M, wq@132M, wv@136M
  f16_t* qb  = (f16_t*)(ws);
  f16_t* kb  = (f16_t*)(ws + (32ull << 20));
  f16_t* vt  = (f16_t*)(ws + (64ull << 20));
  f16_t* S   = (f16_t*)(ws + (96ull << 20));
  f16_t* P   = (f16_t*)(ws + (160ull << 20));
  f16_t* xb  = (f16_t*)(ws + (96ull << 20));
  f16_t* wkb = (f16_t*)(ws + (128ull << 20));
  f16_t* wqb = (f16_t*)(ws + (132ull << 20));
  f16_t* wvb = (f16_t*)(ws + (136ull << 20));

  k_cvt_all<<<(XN4 + 3 * WN4) / 256, 256, 0, stream>>>(
      (const float4*)x, (const float4*)Wk, (const float4*)Wq, (const float4*)Wv,
      (ushort4*)xb, (ushort4*)wkb, (ushort4*)wqb, (ushort4*)wvb);

  dim3 gp(H_DIM / 256, (B_SZ * T_SEQ) / 256, 3);       // 8 x 32 x 3
  k_proj<<<gp, 512, 0, stream>>>(xb, wqb, wkb, wvb, qb, kb, (u16*)vt);

  dim3 gs(136, B_SZ);                                   // lower-triangle tiles
  k_scores<<<gs, 256, 0, stream>>>(qb, kb, S);
  k_softmax<<<B_SZ * T_SEQ, 256, 0, stream>>>(S, P);
  dim3 gv(T_SEQ / 128, 8, B_SZ);                        // paired m-tiles
  k_pv<<<gv, 256, 0, stream>>>(P, vt, out);
}